// Round 1
// baseline (635.336 us; speedup 1.0000x reference)
//
#include <hip/hip_runtime.h>
#include <math.h>

#define Bb 256
#define Tt 1024
#define Ll 128

// ---------------- numerator kernel ----------------
__global__ __launch_bounds__(256) void crf_num_kernel(
    const float* __restrict__ h, const int* __restrict__ labels,
    const float* __restrict__ mask, const float* __restrict__ trans,
    const float* __restrict__ start_trans, const float* __restrict__ end_trans,
    float* __restrict__ num_out)
{
    const int b = blockIdx.x;
    const int tid = threadIdx.x;
    const int* lab = labels + b * Tt;
    const float* mk = mask + b * Tt;
    const float* hb = h + (size_t)b * Tt * Ll;

    float acc = 0.f;
    float msum = 0.f;
    for (int t = tid; t < Tt; t += 256) {
        int lt = lab[t];
        float mt = mk[t];
        msum += mt;
        if (t < Tt - 1) {
            int lt1 = lab[t + 1];
            acc += hb[t * Ll + lt] * mt + trans[lt * Ll + lt1] * mk[t + 1];
        }
    }
    for (int off = 32; off; off >>= 1) {
        acc  += __shfl_down(acc, off, 64);
        msum += __shfl_down(msum, off, 64);
    }
    __shared__ float racc[4], rmsum[4];
    const int wave = tid >> 6;
    if ((tid & 63) == 0) { racc[wave] = acc; rmsum[wave] = msum; }
    __syncthreads();
    if (tid == 0) {
        float a = racc[0] + racc[1] + racc[2] + racc[3];
        float m = rmsum[0] + rmsum[1] + rmsum[2] + rmsum[3];
        int last_idx = (int)(m + 0.5f) - 1;
        if (last_idx < 0) last_idx = 0;
        if (last_idx > Tt - 1) last_idx = Tt - 1;
        int last_lab = lab[last_idx];
        float num = a + start_trans[lab[0]];
        num += hb[(Tt - 1) * Ll + last_lab] * mk[Tt - 1];
        num += end_trans[last_lab];
        num_out[b] = num;
    }
}

// ---------------- denominator (forward scan) kernel ----------------
// 256 blocks (one per batch) x 256 threads (4 waves).
// thread (j = tid&127, half = tid>>7) owns output column j over i-range [half*64, half*64+64)
// Et = exp(trans) fragment kept in 64 VGPRs per thread.
// Shift trick: S_t = score_{t-1}[0] + 16 (uniform, lag-1), triple-buffered in LDS so
// the shift applied at exp time and added back at combine time are identical.
__global__ __launch_bounds__(256) void crf_den_kernel(
    const float* __restrict__ h, const float* __restrict__ mask,
    const float* __restrict__ trans, const float* __restrict__ start_trans,
    const float* __restrict__ end_trans, const float* __restrict__ num_in,
    float* __restrict__ out)
{
    __shared__ float p_lds[Ll];
    __shared__ float part_lds[2][Ll];
    __shared__ float sc0_lds[3];
    __shared__ float red[4];

    const int b = blockIdx.x;
    const int tid = threadIdx.x;
    const int j = tid & (Ll - 1);
    const int half = tid >> 7;
    const float SH = 16.0f;

    const float* hb = h + (size_t)b * Tt * Ll;
    const float* mk = mask + b * Tt;

    // exp(trans) column fragment -> registers
    float et[64];
    #pragma unroll
    for (int k = 0; k < 64; ++k)
        et[k] = __expf(trans[(half * 64 + k) * Ll + j]);

    // bootstrap t = 0
    float score = 0.f;
    float hc = 0.f, hn = 0.f;
    if (tid < Ll) {
        score = start_trans[j] + hb[j];
        if (tid == 0) { sc0_lds[0] = score; sc0_lds[2] = score; }
    }
    __syncthreads();
    if (tid < Ll) {
        float S0 = sc0_lds[0] + SH;
        p_lds[j] = __expf(score - S0);
        hc = hb[1 * Ll + j];
        hn = hb[2 * Ll + j];
    }
    __syncthreads();

    for (int t = 1; t < Tt; ++t) {
        // ---- matvec phase (all 256 threads) ----
        float acc = 0.f;
        const float4* pp = (const float4*)(p_lds + (half << 6));
        #pragma unroll
        for (int k2 = 0; k2 < 16; ++k2) {
            float4 pv = pp[k2];
            acc = fmaf(pv.x, et[4 * k2 + 0], acc);
            acc = fmaf(pv.y, et[4 * k2 + 1], acc);
            acc = fmaf(pv.z, et[4 * k2 + 2], acc);
            acc = fmaf(pv.w, et[4 * k2 + 3], acc);
        }
        part_lds[half][j] = acc;
        // prefetch h for t+2 in the shadow of the matvec
        float hp = 0.f;
        if (tid < Ll && t + 2 < Tt) hp = hb[(t + 2) * Ll + j];
        __syncthreads();
        // ---- combine phase (threads 0..127) ----
        if (tid < Ll) {
            float s = part_lds[0][j] + part_lds[1][j];
            float Sback = sc0_lds[(t + 1) % 3] + SH; // shift applied to current p (= S_{t-1})
            float Sfwd  = sc0_lds[(t - 1) % 3] + SH; // shift for new p (= S_t)
            float sc_upd = hc + Sback + __logf(s);
            float mt = mk[t];
            float sc_new = mt * sc_upd + (1.f - mt) * score;
            score = sc_new;
            p_lds[j] = __expf(score - Sfwd);
            if (tid == 0) sc0_lds[t % 3] = score;
            hc = hn; hn = hp;
        }
        __syncthreads();
    }

    // ---- final logsumexp over score + end_trans ----
    float v = (tid < Ll) ? (score + end_trans[j]) : -1e30f;
    float m = v;
    for (int off = 32; off; off >>= 1) m = fmaxf(m, __shfl_xor(m, off, 64));
    if (tid < Ll && (tid & 63) == 0) red[tid >> 6] = m;
    __syncthreads();
    float M = fmaxf(red[0], red[1]);
    __syncthreads();
    float e = (tid < Ll) ? __expf(v - M) : 0.f;
    for (int off = 32; off; off >>= 1) e += __shfl_xor(e, off, 64);
    if (tid < Ll && (tid & 63) == 0) red[tid >> 6] = e;
    __syncthreads();
    if (tid == 0) {
        float den = M + __logf(red[0] + red[1]);
        out[b] = num_in[b] - den;
    }
}

extern "C" void kernel_launch(void* const* d_in, const int* in_sizes, int n_in,
                              void* d_out, int out_size, void* d_ws, size_t ws_size,
                              hipStream_t stream) {
    const float* h           = (const float*)d_in[0];
    const int*   labels      = (const int*)d_in[1];
    const float* mask        = (const float*)d_in[2];
    const float* trans       = (const float*)d_in[3];
    const float* start_trans = (const float*)d_in[4];
    const float* end_trans   = (const float*)d_in[5];
    float* out    = (float*)d_out;
    float* num_ws = (float*)d_ws;

    crf_num_kernel<<<Bb, 256, 0, stream>>>(h, labels, mask, trans, start_trans, end_trans, num_ws);
    crf_den_kernel<<<Bb, 256, 0, stream>>>(h, mask, trans, start_trans, end_trans, num_ws, out);
}

// Round 2
// 602.923 us; speedup vs baseline: 1.0538x; 1.0538x over previous
//
#include <hip/hip_runtime.h>
#include <math.h>

#define Bb 256
#define Tt 1024
#define Ll 128

// ---------------- numerator kernel ----------------
__global__ __launch_bounds__(256) void crf_num_kernel(
    const float* __restrict__ h, const int* __restrict__ labels,
    const float* __restrict__ mask, const float* __restrict__ trans,
    const float* __restrict__ start_trans, const float* __restrict__ end_trans,
    float* __restrict__ num_out)
{
    const int b = blockIdx.x;
    const int tid = threadIdx.x;
    const int* lab = labels + b * Tt;
    const float* mk = mask + b * Tt;
    const float* hb = h + (size_t)b * Tt * Ll;

    float acc = 0.f;
    float msum = 0.f;
    for (int t = tid; t < Tt; t += 256) {
        int lt = lab[t];
        float mt = mk[t];
        msum += mt;
        if (t < Tt - 1) {
            int lt1 = lab[t + 1];
            acc += hb[t * Ll + lt] * mt + trans[lt * Ll + lt1] * mk[t + 1];
        }
    }
    for (int off = 32; off; off >>= 1) {
        acc  += __shfl_down(acc, off, 64);
        msum += __shfl_down(msum, off, 64);
    }
    __shared__ float racc[4], rmsum[4];
    const int wave = tid >> 6;
    if ((tid & 63) == 0) { racc[wave] = acc; rmsum[wave] = msum; }
    __syncthreads();
    if (tid == 0) {
        float a = racc[0] + racc[1] + racc[2] + racc[3];
        float m = rmsum[0] + rmsum[1] + rmsum[2] + rmsum[3];
        int last_idx = (int)(m + 0.5f) - 1;
        if (last_idx < 0) last_idx = 0;
        if (last_idx > Tt - 1) last_idx = Tt - 1;
        int last_lab = lab[last_idx];
        float num = a + start_trans[lab[0]];
        num += hb[(Tt - 1) * Ll + last_lab] * mk[Tt - 1];
        num += end_trans[last_lab];
        num_out[b] = num;
    }
}

// ---------------- denominator (forward scan) kernel ----------------
// 256 blocks (one per batch) x 256 threads (4 waves).
// Wave w owns columns [32w, 32w+32); lane pair (2c, 2c+1) owns one column j,
// split over i in [0,64) / [64,128). et fragment = 64 f32 VGPRs per lane.
// Pair-reduce via __shfl_xor(acc,1) -> no cross-wave partials, ONE barrier/step.
// p double-buffered in LDS; shift S_t = score_{t-1}[0] + 16 triple-buffered.
__global__ __launch_bounds__(256, 1) void crf_den_kernel(
    const float* __restrict__ h, const float* __restrict__ mask,
    const float* __restrict__ trans, const float* __restrict__ start_trans,
    const float* __restrict__ end_trans, const float* __restrict__ num_in,
    float* __restrict__ out)
{
    __shared__ float p_lds[2][Ll];
    __shared__ float mk_lds[Tt];
    __shared__ float sc0[3];
    __shared__ float redm[4], reds[4];

    const int b = blockIdx.x;
    const int tid = threadIdx.x;
    const int wave = tid >> 6;
    const int lane = tid & 63;
    const int j = (wave << 5) + (lane >> 1);   // column 0..127
    const int ih = (lane & 1) << 6;            // i-range base: 0 or 64
    const float SH = 16.0f;

    const float* hb = h + (size_t)b * Tt * Ll;

    // stage mask row into LDS
    for (int t = tid; t < Tt; t += 256) mk_lds[t] = mask[b * Tt + t];

    // exp(trans) fragment -> 64 VGPRs
    float et[64];
    #pragma unroll
    for (int k = 0; k < 64; ++k)
        et[k] = __expf(trans[(ih + k) * Ll + j]);

    // bootstrap t = 0
    float score = start_trans[j] + hb[j];
    float hc = hb[1 * Ll + j];
    float hn = hb[2 * Ll + j];
    if (tid == 0) { sc0[0] = score; sc0[2] = score; }
    __syncthreads();
    if (!(lane & 1)) p_lds[0][j] = __expf(score - (sc0[0] + SH));
    __syncthreads();

    int cbuf = 0;
    for (int t = 1; t < Tt; ++t) {
        // issue h prefetch for t+2 early
        float hp = 0.f;
        if (t + 2 < Tt) hp = hb[(t + 2) * Ll + j];

        // matvec: 64 FMAs over this lane's i-half, p read as broadcast float4
        const float4* pp = (const float4*)(p_lds[cbuf] + ih);
        float a0 = 0.f, a1 = 0.f, a2 = 0.f, a3 = 0.f;
        #pragma unroll
        for (int k2 = 0; k2 < 16; ++k2) {
            float4 pv = pp[k2];
            a0 = fmaf(pv.x, et[4 * k2 + 0], a0);
            a1 = fmaf(pv.y, et[4 * k2 + 1], a1);
            a2 = fmaf(pv.z, et[4 * k2 + 2], a2);
            a3 = fmaf(pv.w, et[4 * k2 + 3], a3);
        }
        float acc = (a0 + a1) + (a2 + a3);
        acc += __shfl_xor(acc, 1, 64);   // pair-reduce: both lanes get full sum

        // combine (both lanes of pair, redundant)
        float Sback = sc0[(t + 1) % 3] + SH;  // shift inside current p  (S_{t-1})
        float Sfwd  = sc0[(t + 2) % 3] + SH;  // shift for new p         (S_t)
        float mt = mk_lds[t];
        float upd = hc + Sback + __logf(acc);
        score = mt * upd + (1.f - mt) * score;
        if (!(lane & 1)) p_lds[cbuf ^ 1][j] = __expf(score - Sfwd);
        if (tid == 0) sc0[t % 3] = score;     // tid 0 owns column 0
        hc = hn; hn = hp;
        __syncthreads();
        cbuf ^= 1;
    }

    // ---- final logsumexp over score + end_trans ----
    float v = score + end_trans[j];
    float mval = ((lane & 1) == 0) ? v : -1e30f;
    #pragma unroll
    for (int off = 32; off; off >>= 1) mval = fmaxf(mval, __shfl_xor(mval, off, 64));
    if (lane == 0) redm[wave] = mval;
    __syncthreads();
    float M = fmaxf(fmaxf(redm[0], redm[1]), fmaxf(redm[2], redm[3]));
    float e = ((lane & 1) == 0) ? __expf(v - M) : 0.f;
    #pragma unroll
    for (int off = 32; off; off >>= 1) e += __shfl_xor(e, off, 64);
    if (lane == 0) reds[wave] = e;
    __syncthreads();
    if (tid == 0) {
        float den = M + __logf(reds[0] + reds[1] + reds[2] + reds[3]);
        out[b] = num_in[b] - den;
    }
}

extern "C" void kernel_launch(void* const* d_in, const int* in_sizes, int n_in,
                              void* d_out, int out_size, void* d_ws, size_t ws_size,
                              hipStream_t stream) {
    const float* h           = (const float*)d_in[0];
    const int*   labels      = (const int*)d_in[1];
    const float* mask        = (const float*)d_in[2];
    const float* trans       = (const float*)d_in[3];
    const float* start_trans = (const float*)d_in[4];
    const float* end_trans   = (const float*)d_in[5];
    float* out    = (float*)d_out;
    float* num_ws = (float*)d_ws;

    crf_num_kernel<<<Bb, 256, 0, stream>>>(h, labels, mask, trans, start_trans, end_trans, num_ws);
    crf_den_kernel<<<Bb, 256, 0, stream>>>(h, mask, trans, start_trans, end_trans, num_ws, out);
}

// Round 3
// 588.204 us; speedup vs baseline: 1.0801x; 1.0250x over previous
//
#include <hip/hip_runtime.h>
#include <math.h>

#define Bb 256
#define Tt 1024
#define Ll 128

// ---------------- exp(trans) transpose precompute ----------------
// expT[j*128 + i] = exp(trans[i*128 + j])
__global__ __launch_bounds__(256) void crf_expT_kernel(
    const float* __restrict__ trans, float* __restrict__ expT)
{
    int idx = blockIdx.x * 256 + threadIdx.x;   // idx = j*128 + i
    if (idx < Ll * Ll) {
        int jj = idx >> 7;
        int ii = idx & (Ll - 1);
        expT[idx] = __expf(trans[ii * Ll + jj]);
    }
}

// ---------------- numerator kernel ----------------
__global__ __launch_bounds__(256) void crf_num_kernel(
    const float* __restrict__ h, const int* __restrict__ labels,
    const float* __restrict__ mask, const float* __restrict__ trans,
    const float* __restrict__ start_trans, const float* __restrict__ end_trans,
    float* __restrict__ num_out)
{
    const int b = blockIdx.x;
    const int tid = threadIdx.x;
    const int* lab = labels + b * Tt;
    const float* mk = mask + b * Tt;
    const float* hb = h + (size_t)b * Tt * Ll;

    float acc = 0.f;
    float msum = 0.f;
    for (int t = tid; t < Tt; t += 256) {
        int lt = lab[t];
        float mt = mk[t];
        msum += mt;
        if (t < Tt - 1) {
            int lt1 = lab[t + 1];
            acc += hb[t * Ll + lt] * mt + trans[lt * Ll + lt1] * mk[t + 1];
        }
    }
    for (int off = 32; off; off >>= 1) {
        acc  += __shfl_down(acc, off, 64);
        msum += __shfl_down(msum, off, 64);
    }
    __shared__ float racc[4], rmsum[4];
    const int wave = tid >> 6;
    if ((tid & 63) == 0) { racc[wave] = acc; rmsum[wave] = msum; }
    __syncthreads();
    if (tid == 0) {
        float a = racc[0] + racc[1] + racc[2] + racc[3];
        float m = rmsum[0] + rmsum[1] + rmsum[2] + rmsum[3];
        int last_idx = (int)(m + 0.5f) - 1;
        if (last_idx < 0) last_idx = 0;
        if (last_idx > Tt - 1) last_idx = Tt - 1;
        int last_lab = lab[last_idx];
        float num = a + start_trans[lab[0]];
        num += hb[(Tt - 1) * Ll + last_lab] * mk[Tt - 1];
        num += end_trans[last_lab];
        num_out[b] = num;
    }
}

// ---------------- denominator (forward scan) kernel ----------------
// 256 blocks (one per batch) x 256 threads (4 waves).
// Wave w owns columns [32w, 32w+32); lane pair (2c, 2c+1) owns one column j,
// split over i in [0,64) / [64,128). exp(trans) fragment = 16 NAMED float4
// locals (e0..e15) loaded once from the precomputed transposed expT —
// guaranteed VGPR residency (round-2's et[64] array was demoted, VGPR=48).
// Pair-reduce via __shfl_xor(acc,1) -> ONE barrier/step.
// p double-buffered in LDS; shift S_t = score_{t-1}[0] + 16 triple-buffered.
__global__ __launch_bounds__(256, 1) void crf_den_kernel(
    const float* __restrict__ h, const float* __restrict__ mask,
    const float* __restrict__ expT, const float* __restrict__ start_trans,
    const float* __restrict__ end_trans, const float* __restrict__ num_in,
    float* __restrict__ out)
{
    __shared__ float p_lds[2][Ll];
    __shared__ float mk_lds[Tt];
    __shared__ float sc0[3];
    __shared__ float redm[4], reds[4];

    const int b = blockIdx.x;
    const int tid = threadIdx.x;
    const int wave = tid >> 6;
    const int lane = tid & 63;
    const int j = (wave << 5) + (lane >> 1);   // column 0..127
    const int ih = (lane & 1) << 6;            // i-range base: 0 or 64
    const float SH = 16.0f;

    const float* hb = h + (size_t)b * Tt * Ll;

    // stage mask row into LDS
    for (int t = tid; t < Tt; t += 256) mk_lds[t] = mask[b * Tt + t];

    // exp(trans) fragment: 16 named float4 = 64 VGPRs, contiguous load
    const float4* ep = (const float4*)(expT + j * Ll + ih);
    float4 e0  = ep[0],  e1  = ep[1],  e2  = ep[2],  e3  = ep[3];
    float4 e4  = ep[4],  e5  = ep[5],  e6  = ep[6],  e7  = ep[7];
    float4 e8  = ep[8],  e9  = ep[9],  e10 = ep[10], e11 = ep[11];
    float4 e12 = ep[12], e13 = ep[13], e14 = ep[14], e15 = ep[15];

    // bootstrap t = 0
    float score = start_trans[j] + hb[j];
    float hc = hb[1 * Ll + j];
    float hn = hb[2 * Ll + j];
    if (tid == 0) { sc0[0] = score; sc0[2] = score; }
    __syncthreads();
    if (!(lane & 1)) p_lds[0][j] = __expf(score - (sc0[0] + SH));
    __syncthreads();

    int cbuf = 0;
    for (int t = 1; t < Tt; ++t) {
        // issue h prefetch for t+2 early
        float hp = (t + 2 < Tt) ? hb[(t + 2) * Ll + j] : 0.f;

        // matvec: 64 FMAs over this lane's i-half, p read as broadcast float4
        const float4* pp = (const float4*)(p_lds[cbuf] + ih);
        float a0 = 0.f, a1 = 0.f, a2 = 0.f, a3 = 0.f;
#define FMA4(E, K) { float4 pv = pp[K];              \
        a0 = fmaf(pv.x, E.x, a0);                    \
        a1 = fmaf(pv.y, E.y, a1);                    \
        a2 = fmaf(pv.z, E.z, a2);                    \
        a3 = fmaf(pv.w, E.w, a3); }
        FMA4(e0, 0)   FMA4(e1, 1)   FMA4(e2, 2)   FMA4(e3, 3)
        FMA4(e4, 4)   FMA4(e5, 5)   FMA4(e6, 6)   FMA4(e7, 7)
        FMA4(e8, 8)   FMA4(e9, 9)   FMA4(e10, 10) FMA4(e11, 11)
        FMA4(e12, 12) FMA4(e13, 13) FMA4(e14, 14) FMA4(e15, 15)
#undef FMA4
        float acc = (a0 + a1) + (a2 + a3);
        acc += __shfl_xor(acc, 1, 64);   // pair-reduce: both lanes get full sum

        // combine (both lanes of pair, redundant)
        float Sback = sc0[(t + 1) % 3] + SH;  // shift inside current p  (S_{t-2} base -> see ring proof)
        float Sfwd  = sc0[(t + 2) % 3] + SH;  // shift for new p         (score_{t-1} base)
        float mt = mk_lds[t];
        float upd = hc + Sback + __logf(acc);
        score = mt * upd + (1.f - mt) * score;
        if (!(lane & 1)) p_lds[cbuf ^ 1][j] = __expf(score - Sfwd);
        if (tid == 0) sc0[t % 3] = score;     // tid 0 owns column 0
        hc = hn; hn = hp;
        __syncthreads();
        cbuf ^= 1;
    }

    // ---- final logsumexp over score + end_trans ----
    float v = score + end_trans[j];
    float mval = ((lane & 1) == 0) ? v : -1e30f;
    #pragma unroll
    for (int off = 32; off; off >>= 1) mval = fmaxf(mval, __shfl_xor(mval, off, 64));
    if (lane == 0) redm[wave] = mval;
    __syncthreads();
    float M = fmaxf(fmaxf(redm[0], redm[1]), fmaxf(redm[2], redm[3]));
    float e = ((lane & 1) == 0) ? __expf(v - M) : 0.f;
    #pragma unroll
    for (int off = 32; off; off >>= 1) e += __shfl_xor(e, off, 64);
    if (lane == 0) reds[wave] = e;
    __syncthreads();
    if (tid == 0) {
        float den = M + __logf(reds[0] + reds[1] + reds[2] + reds[3]);
        out[b] = num_in[b] - den;
    }
}

extern "C" void kernel_launch(void* const* d_in, const int* in_sizes, int n_in,
                              void* d_out, int out_size, void* d_ws, size_t ws_size,
                              hipStream_t stream) {
    const float* h           = (const float*)d_in[0];
    const int*   labels      = (const int*)d_in[1];
    const float* mask        = (const float*)d_in[2];
    const float* trans       = (const float*)d_in[3];
    const float* start_trans = (const float*)d_in[4];
    const float* end_trans   = (const float*)d_in[5];
    float* out    = (float*)d_out;
    float* num_ws = (float*)d_ws;                 // [0, 256)       num results
    float* expT   = (float*)d_ws + 256;           // [256, 256+16384) exp(trans)^T

    crf_expT_kernel<<<(Ll * Ll + 255) / 256, 256, 0, stream>>>(trans, expT);
    crf_num_kernel<<<Bb, 256, 0, stream>>>(h, labels, mask, trans, start_trans, end_trans, num_ws);
    crf_den_kernel<<<Bb, 256, 0, stream>>>(h, mask, expT, start_trans, end_trans, num_ws, out);
}